// Round 3
// baseline (435.004 us; speedup 1.0000x reference)
//
#include <hip/hip_runtime.h>
#include <hip/hip_bf16.h>
#include <cstdint>
#include <cstddef>

#define N 4096
#define NN ((size_t)N * (size_t)N)

typedef int int4v __attribute__((ext_vector_type(4)));

__device__ inline void async16(const void* g, void* lds) {
    __builtin_amdgcn_global_load_lds(
        (const __attribute__((address_space(1))) void*)g,
        (__attribute__((address_space(3))) void*)lds, 16, 0, 0);
}

// ---------------- kernel 1: straight-through flip, float4, op-order identical to numpy ref ----
__global__ void mod_kernel(const float4* __restrict__ ori,
                           const float4* __restrict__ clp,
                           const float4* __restrict__ u,
                           float4* __restrict__ out,
                           double* __restrict__ accs) {
    size_t i = (size_t)blockIdx.x * blockDim.x + threadIdx.x;
    float4 o4 = ori[i], p4 = clp[i], u4 = u[i];
    float po[4] = {p4.x, p4.y, p4.z, p4.w};
    float uo[4] = {u4.x, u4.y, u4.z, u4.w};
    float oo[4] = {o4.x, o4.y, o4.z, o4.w};
    float ro[4];
    #pragma unroll
    for (int k = 0; k < 4; ++k) {
        float p = fminf(fmaxf(po[k], 1e-10f), 1.0f - 1e-10f);
        float logits = logf(p) - log1pf(-p);
        float uu = uo[k];
        float noise = logf(uu) - log1pf(-uu);
        float y = (logits + noise) / 0.2f;
        float soft = 1.0f / (1.0f + expf(-y));
        float hard = rintf(soft);
        float o = oo[k];
        ro[k] = o + hard * (-2.0f * o);
    }
    out[i] = make_float4(ro[0], ro[1], ro[2], ro[3]);
    if (blockIdx.x == 0 && threadIdx.x < 2) accs[threadIdx.x] = 0.0;
}

// ---------------- kernel 2: A = mod + mod^T - diag(col) as i8: A, AT, |A|, |A|T (diag fused) ---
__global__ void build_A8(const float* __restrict__ mod,
                         signed char* __restrict__ A,
                         signed char* __restrict__ AT,
                         signed char* __restrict__ Aa,
                         signed char* __restrict__ ATa) {
    __shared__ float tji[32][33];        // tji[j-local][i-local] = mod[j][i]
    __shared__ float dloc[32];           // dloc[j-local] = mod[j][j]
    __shared__ signed char cv[32][36];   // cv[i-local][j-local] = A value
    const int bi = blockIdx.x * 32;
    const int bj = blockIdx.y * 32;
    const int tx = threadIdx.x;   // 0..7  (groups of 4 cols)
    const int ty = threadIdx.y;   // 0..31 (rows)
    {
        const float4 v = *(const float4*)&mod[(size_t)(bj + ty) * N + bi + tx * 4];
        tji[ty][tx * 4 + 0] = v.x; tji[ty][tx * 4 + 1] = v.y;
        tji[ty][tx * 4 + 2] = v.z; tji[ty][tx * 4 + 3] = v.w;
    }
    if (tx == 0) dloc[ty] = mod[(size_t)(bj + ty) * N + bj + ty];
    __syncthreads();
    const float4 mv = *(const float4*)&mod[(size_t)(bi + ty) * N + bj + tx * 4];
    float m4[4] = {mv.x, mv.y, mv.z, mv.w};
    int pkA = 0, pkAa = 0;
    #pragma unroll
    for (int k = 0; k < 4; ++k) {
        int jl = tx * 4 + k;
        float a = m4[k] + tji[jl][ty] - dloc[jl];  // exact small integer
        int ai = (int)a;
        cv[ty][jl] = (signed char)ai;
        int au = ai < 0 ? -ai : ai;
        pkA  |= (ai & 255) << (8 * k);
        pkAa |= (au & 255) << (8 * k);
    }
    *(int*)&A [(size_t)(bi + ty) * N + bj + tx * 4] = pkA;
    *(int*)&Aa[(size_t)(bi + ty) * N + bj + tx * 4] = pkAa;
    __syncthreads();
    int pkT = 0, pkTa = 0;
    #pragma unroll
    for (int k = 0; k < 4; ++k) {
        int il = tx * 4 + k;
        int v = cv[il][ty];                 // A[i-local=il][j-local=ty] -> AT[j][i]
        int va = v < 0 ? -v : v;
        pkT  |= (v  & 255) << (8 * k);
        pkTa |= (va & 255) << (8 * k);
    }
    *(int*)&AT [(size_t)(bj + ty) * N + bi + tx * 4] = pkT;
    *(int*)&ATa[(size_t)(bj + ty) * N + bi + tx * 4] = pkTa;
}

// ---------------- kernel 3: i8 GEMM-trace, BK=128, lo/hi half-buffers, XOR swizzle ----------------
// acc[z] = sum_{i,k} (M.M)[i,k] * M[k,i], M = A (z=0) or |A| (z=1). Exact integer math.
// LDS per matrix: lo half (K 0..63) 128 rows x 64B, hi half (K 64..127) same. Row stride 64B
// keeps the round-2 conflict-free swizzle: slot_stored = chunk ^ ((row>>1)&3).
__global__ __launch_bounds__(256) void gemm_trace_i8(const signed char* __restrict__ Ag,
                                                     const signed char* __restrict__ ATg,
                                                     const signed char* __restrict__ Aag,
                                                     const signed char* __restrict__ ATag,
                                                     double* __restrict__ accs) {
    __shared__ int4v As4[1024];   // [0..511]=lo, [512..1023]=hi
    __shared__ int4v Bs4[1024];
    __shared__ int red[4];
    const int z = blockIdx.z;
    const signed char* Asrc = z ? Aag  : Ag;    // M rows   (i-panel)
    const signed char* Bsrc = z ? ATag : ATg;   // MT rows  (k-panel), B[k][n] = MT[n][k]
    const int i0 = blockIdx.y * 128;
    const int k0 = blockIdx.x * 128;
    const int t = threadIdx.x;
    const int lane = t & 63;
    const int wave = t >> 6;
    const int quad = lane >> 4;
    const int col  = lane & 15;
    const int wr = (wave >> 1) * 64;
    const int wc = (wave & 1) * 64;
    signed char* Asc = (signed char*)As4;
    signed char* Bsc = (signed char*)Bs4;

    // staging: per matrix 1024 chunks of 16B. it0: lo rows 0..63, it1: lo rows 64..127,
    // it2: hi rows 0..63, it3: hi rows 64..127. id = it*256 + t; LDS addr = id*16 (contiguous,
    // wave-uniform base + lane*16). Global chunk c = (t&3) ^ ((row>>1)&3), same for all its.
    const int r0 = t >> 2;               // 0..63
    const int s0 = t & 3;
    const int c0 = s0 ^ ((r0 >> 1) & 3);
    const signed char* gA = Asrc + (size_t)(i0 + r0) * N + c0 * 16;
    const signed char* gB = Bsrc + (size_t)(k0 + r0) * N + c0 * 16;
    const int ldst = t * 16;

    int4v acc[4][4];
    #pragma unroll
    for (int a = 0; a < 4; ++a)
        #pragma unroll
        for (int b = 0; b < 4; ++b)
            acc[a][b] = (int4v){0, 0, 0, 0};

    const int fsw = ((quad ^ ((col >> 1) & 3)) << 4);

    for (int kb = 0; kb < N; kb += 128) {
        __syncthreads();
        const signed char* ga = gA + kb;
        const signed char* gb = gB + kb;
        async16(ga,              Asc + ldst);                 // lo, rows 0..63
        async16(ga + 64 * N,     Asc + 4096  + ldst);         // lo, rows 64..127
        async16(ga + 64,         Asc + 8192  + ldst);         // hi, rows 0..63
        async16(ga + 64 * N + 64, Asc + 12288 + ldst);        // hi, rows 64..127
        async16(gb,              Bsc + ldst);
        async16(gb + 64 * N,     Bsc + 4096  + ldst);
        async16(gb + 64,         Bsc + 8192  + ldst);
        async16(gb + 64 * N + 64, Bsc + 12288 + ldst);
        __syncthreads();
        int4v af0[4], af1[4], bf0[4], bf1[4];
        #pragma unroll
        for (int tr = 0; tr < 4; ++tr) {
            const int ra = (wr + tr * 16 + col) << 6;
            af0[tr] = *(const int4v*)(Asc + ra + fsw);
            af1[tr] = *(const int4v*)(Asc + 8192 + ra + fsw);
        }
        #pragma unroll
        for (int tc = 0; tc < 4; ++tc) {
            const int rb = (wc + tc * 16 + col) << 6;
            bf0[tc] = *(const int4v*)(Bsc + rb + fsw);
            bf1[tc] = *(const int4v*)(Bsc + 8192 + rb + fsw);
        }
        #pragma unroll
        for (int tr = 0; tr < 4; ++tr)
            #pragma unroll
            for (int tc = 0; tc < 4; ++tc)
                acc[tr][tc] = __builtin_amdgcn_mfma_i32_16x16x64_i8(af0[tr], bf0[tc], acc[tr][tc], 0, 0, 0);
        #pragma unroll
        for (int tr = 0; tr < 4; ++tr)
            #pragma unroll
            for (int tc = 0; tc < 4; ++tc)
                acc[tr][tc] = __builtin_amdgcn_mfma_i32_16x16x64_i8(af1[tr], bf1[tc], acc[tr][tc], 0, 0, 0);
    }

    // trace epilogue: C/D layout col=lane&15, row=quad*4+reg (shape-determined).
    // multiplier M[k,i] = MT[i,k] = Bsrc[i*N + k] (already |.| for z=1). Exact int32.
    int part = 0;
    #pragma unroll
    for (int tr = 0; tr < 4; ++tr) {
        #pragma unroll
        for (int tc = 0; tc < 4; ++tc) {
            const int ib = i0 + wr + tr * 16 + quad * 4;
            const int kk = k0 + wc + tc * 16 + col;
            #pragma unroll
            for (int r = 0; r < 4; ++r)
                part += acc[tr][tc][r] * (int)Bsrc[(size_t)(ib + r) * N + kk];
        }
    }
    #pragma unroll
    for (int off = 32; off > 0; off >>= 1)
        part += __shfl_down(part, off, 64);
    if (lane == 0) red[wave] = part;
    __syncthreads();
    if (t == 0) {
        int tot = red[0] + red[1] + red[2] + red[3];
        atomicAdd(&accs[z], (double)tot);
    }
}

// ---------------- kernel 4: balance ----------------
__global__ void finalize_kernel(const double* __restrict__ accs, float* __restrict__ out) {
    out[NN] = (float)(0.5 * (1.0 + accs[0] / accs[1]));
}

extern "C" void kernel_launch(void* const* d_in, const int* in_sizes, int n_in,
                              void* d_out, int out_size, void* d_ws, size_t ws_size,
                              hipStream_t stream) {
    const float* ori = (const float*)d_in[0];
    const float* clp = (const float*)d_in[1];
    const float* u   = (const float*)d_in[2];
    float* out = (float*)d_out;
    char* ws = (char*)d_ws;
    signed char* A8   = (signed char*)ws;                    // 16 MiB
    signed char* AT8  = (signed char*)(ws + NN);             // 16 MiB
    signed char* Aa8  = (signed char*)(ws + 2 * NN);         // 16 MiB
    signed char* ATa8 = (signed char*)(ws + 3 * NN);         // 16 MiB
    double*      accs = (double*)(ws + 4 * NN);              // 16 B

    mod_kernel<<<dim3((unsigned)(NN / 1024)), 256, 0, stream>>>(
        (const float4*)ori, (const float4*)clp, (const float4*)u, (float4*)out, accs);
    build_A8<<<dim3(N / 32, N / 32), dim3(8, 32), 0, stream>>>(out, A8, AT8, Aa8, ATa8);
    gemm_trace_i8<<<dim3(N / 128, N / 128, 2), 256, 0, stream>>>(A8, AT8, Aa8, ATa8, accs);
    finalize_kernel<<<1, 1, 0, stream>>>(accs, out);
}